// Round 4
// baseline (5196.749 us; speedup 1.0000x reference)
//
#include <hip/hip_runtime.h>

// ---------------------------------------------------------------------------
// PointNet++ (defense variant) forward on MI355X.
// B=8, N=4096 -> 2048 -> 512, K=32 neighbors, all fp32 except geometry (fp64:
// positions are multiples of 2^-23 so all squared distances are EXACT in f64;
// selection / FPS ranking therefore matches an np-f64 reference exactly).
// R4: FPS spill fix — __launch_bounds__(256,1) (occupancy irrelevant at 8
// blocks; R1/R3 VGPR=84 proved the compiler spilled the ~160-reg point state)
// + coords kept in f32 regs (x - wx is exact in f32 on the 2^-23 grid).
// ---------------------------------------------------------------------------

#define NB 8

__device__ __forceinline__ unsigned obits(float f) {
  unsigned u = __float_as_uint(f);
  return (u & 0x80000000u) ? ~u : (u | 0x80000000u);
}

static constexpr int CAND = 1024;

// ---------------- radius-KNN: exact top-32 by (d2, idx) lex order -----------
template<int N>
__global__ __launch_bounds__(256) void knn_kernel(const float* __restrict__ pos,
                                                  double rr, int* __restrict__ nbr) {
  const int i = blockIdx.x, b = blockIdx.y;
  const int tid = threadIdx.x;
  const float* __restrict__ pb = pos + (size_t)b * N * 3;
  __shared__ double d2s[N];
  __shared__ unsigned hist[2048];
  __shared__ unsigned scanBuf[256];
  __shared__ int candIdx[CAND];
  __shared__ int candCnt;
  __shared__ int sBinT;

  const double xi = pb[3*i], yi = pb[3*i+1], zi = pb[3*i+2];
  const double si = (xi*xi + yi*yi) + zi*zi;
  for (int t = tid; t < 2048; t += 256) hist[t] = 0u;
  if (tid == 0) candCnt = 0;
  __syncthreads();
  for (int j = tid; j < N; j += 256) {
    double xj = pb[3*j], yj = pb[3*j+1], zj = pb[3*j+2];
    double sj = (xj*xj + yj*yj) + zj*zj;
    double dt = (xi*xj + yi*yj) + zi*zj;
    double d2 = (si + sj) - 2.0*dt;          // exact in f64 (see header note)
    if (j == i) d2 += 1e9;                   // self-exclusion as in reference
    d2s[j] = d2;
    atomicAdd(&hist[obits((float)d2) >> 21], 1u);
  }
  __syncthreads();
  // find smallest bin T with cumulative count >= 32
  unsigned lsum = 0;
  const int base = tid * 8;
#pragma unroll
  for (int q = 0; q < 8; q++) lsum += hist[base + q];
  scanBuf[tid] = lsum;
  __syncthreads();
  for (int ofs = 1; ofs < 256; ofs <<= 1) {
    unsigned v = scanBuf[tid];
    unsigned addv = (tid >= ofs) ? scanBuf[tid - ofs] : 0u;
    __syncthreads();
    scanBuf[tid] = v + addv;
    __syncthreads();
  }
  const unsigned incl = scanBuf[tid], excl = incl - lsum;
  if (excl < 32u && incl >= 32u) {
    unsigned c = excl;
    for (int q = 0; q < 8; q++) {
      c += hist[base + q];
      if (c >= 32u) { sBinT = base + q; break; }
    }
  }
  __syncthreads();
  const int binT = sBinT;
  for (int j = tid; j < N; j += 256) {
    if ((int)(obits((float)d2s[j]) >> 21) <= binT) {
      int p = atomicAdd(&candCnt, 1);
      if (p < CAND) candIdx[p] = j;
    }
  }
  __syncthreads();
  const int M = min(candCnt, CAND);   // M >= 32 by construction; overflow ~impossible
  int* __restrict__ outp = nbr + ((size_t)b * N + i) * 32;
  for (int c = tid; c < M; c += 256) {
    const int j = candIdx[c];
    const double d = d2s[j];
    int rank = 0;
    for (int e = 0; e < M; e++) {
      const int j2 = candIdx[e];
      const double de = d2s[j2];
      rank += (de < d || (de == d && j2 < j)) ? 1 : 0;
    }
    if (rank < 32) outp[rank] = (d <= rr) ? j : -1;  // fold radius-validity into -1
  }
}

// ---------------- farthest point sampling (exact f64, deterministic) --------
// 256 threads (4 waves, 1/SIMD). launch_bounds(256,1): allocator may use the
// full VGPR file — point state must stay in registers (spills dominated R1/R3).
// Coords in f32 (differences exact on the 2^-23 grid); mind in f64 (exact d2).
template<int N, int NOUT>
__global__ __launch_bounds__(256, 1) void fps_kernel(const float* __restrict__ pos,
                                                     int* __restrict__ fi) {
  const int b = blockIdx.x;
  const float* __restrict__ pb = pos + (size_t)b * N * 3;
  constexpr int P = N / 256;
  const int tid = threadIdx.x;
  const int wid = tid >> 6, lane = tid & 63;
  float px[P], py[P], pz[P];
  double mind[P];
  __shared__ float sPos[N][3];
  __shared__ double sVal[2][4];
  __shared__ int    sIdx[2][4];
  // stage positions into LDS (one-time, read-only afterwards)
  for (int t = tid; t < N; t += 256) {
    sPos[t][0] = pb[3*t]; sPos[t][1] = pb[3*t+1]; sPos[t][2] = pb[3*t+2];
  }
  __syncthreads();
  const float x0 = sPos[0][0], y0 = sPos[0][1], z0 = sPos[0][2];
  double bv; int bi;
  {
    double tv[P]; int te[P];
#pragma unroll
    for (int e = 0; e < P; e++) {
      const int j = tid * P + e;
      const float x = sPos[j][0], y = sPos[j][1], z = sPos[j][2];
      px[e] = x; py[e] = y; pz[e] = z;
      const float fdx = x - x0, fdy = y - y0, fdz = z - z0;   // exact in f32
      const double dx = (double)fdx, dy = (double)fdy, dz = (double)fdz;
      const double d = (dx*dx + dy*dy) + dz*dz;               // exact in f64
      mind[e] = d; tv[e] = d; te[e] = e;
    }
#pragma unroll
    for (int s = 1; s < P; s <<= 1)
#pragma unroll
      for (int e = 0; e + s < P; e += 2 * s)
        if (tv[e + s] > tv[e]) { tv[e] = tv[e + s]; te[e] = te[e + s]; }  // tie -> lower e
    bv = tv[0]; bi = tid * P + te[0];
  }
  if (tid == 0) fi[(size_t)b * NOUT] = 0;
  for (int t = 1; t < NOUT; t++) {
    // wave-level lex-max reduce of (val, idx): max val, tie -> min idx
    double v = bv; int idx = bi;
#pragma unroll
    for (int o = 32; o; o >>= 1) {
      const double ov = __shfl_down(v, o);
      const int    oi = __shfl_down(idx, o);
      if (ov > v || (ov == v && oi < idx)) { v = ov; idx = oi; }
    }
    const int pp = t & 1;
    if (lane == 0) { sVal[pp][wid] = v; sIdx[pp][wid] = idx; }
    __syncthreads();   // the only barrier per iteration (partials double-buffered)
    // all threads redundantly reduce the 4 wave partials (2-level tree)
    double v0 = sVal[pp][0], v1 = sVal[pp][1], v2 = sVal[pp][2], v3 = sVal[pp][3];
    int    i0 = sIdx[pp][0], i1 = sIdx[pp][1], i2 = sIdx[pp][2], i3 = sIdx[pp][3];
    if (v1 > v0 || (v1 == v0 && i1 < i0)) { v0 = v1; i0 = i1; }
    if (v3 > v2 || (v3 == v2 && i3 < i2)) { v2 = v3; i2 = i3; }
    if (v2 > v0 || (v2 == v0 && i2 < i0)) { v0 = v2; i0 = i2; }
    const int ii = i0;
    if (tid == 0) fi[(size_t)b * NOUT + t] = ii;
    // winner coords: conflict-free same-address LDS broadcast
    const float wx = sPos[ii][0], wy = sPos[ii][1], wz = sPos[ii][2];
    // fused update + pairwise-tree rescan
    double tv[P]; int te[P];
#pragma unroll
    for (int e = 0; e < P; e++) {
      const float fdx = px[e] - wx, fdy = py[e] - wy, fdz = pz[e] - wz;  // exact
      const double dx = (double)fdx, dy = (double)fdy, dz = (double)fdz;
      const double nd = (dx*dx + dy*dy) + dz*dz;
      double mn = mind[e];
      mn = nd < mn ? nd : mn;
      mind[e] = mn;
      tv[e] = mn; te[e] = e;
    }
#pragma unroll
    for (int s = 1; s < P; s <<= 1)
#pragma unroll
      for (int e = 0; e + s < P; e += 2 * s)
        if (tv[e + s] > tv[e]) { tv[e] = tv[e + s]; te[e] = te[e + s]; }  // tie -> lower e
    bv = tv[0]; bi = tid * P + te[0];
  }
}

// ---------------- gather rows by fps indices --------------------------------
template<int CIN>
__global__ void gather_kernel(const float* __restrict__ X, const float* __restrict__ pos,
                              const int* __restrict__ fi, int N, int M,
                              float* __restrict__ Xg, float* __restrict__ posg) {
  const int row = blockIdx.x;
  const int b = row / M;
  const int tid = threadIdx.x;
  const int j = fi[row];
  if (tid < CIN) Xg[(size_t)row * CIN + tid] = X[((size_t)b * N + j) * CIN + tid];
  if (tid < 3) posg[(size_t)row * 3 + tid] = pos[((size_t)b * N + j) * 3 + tid];
}

// ---------------- per-source-point projection U = x*W1[:CIN] + b1 -----------
template<int CIN, int H>
__global__ void preproj_kernel(const float* __restrict__ X, const float* __restrict__ W,
                               const float* __restrict__ bias, float* __restrict__ U) {
  const int row = blockIdx.x;
  const int tid = threadIdx.x;
  __shared__ float sx[CIN];
  if (tid < CIN) sx[tid] = X[(size_t)row * CIN + tid];
  __syncthreads();
  float a = bias[tid];
  for (int f = 0; f < CIN; f++) a = fmaf(sx[f], W[f * H + tid], a);
  U[(size_t)row * H + tid] = a;
}

// ---------------- fused PointConv (edge MLP + masked max + relu) ------------
// threads = 256 = 4 k-groups x 64 c-lanes; each thread: 8 k's x (C/64) c's.
template<int H, int C, bool HASX>
__global__ __launch_bounds__(256) void conv_kernel(
    const float* __restrict__ pos, int Np,
    const int* __restrict__ nbr,
    const float* __restrict__ U,        // [B*Np, H] (x*W1x + b1) or nullptr
    const float* __restrict__ Wrel,     // rel rows of W1: [3][H]
    const float* __restrict__ b1,       // used only when !HASX
    const float* __restrict__ W2, const float* __restrict__ b2,
    float* __restrict__ out) {
  constexpr int HCHUNK = 4096 / C;
  constexpr int CC = C / 64;
  const int i = blockIdx.x, b = blockIdx.y;
  const int tid = threadIdx.x;
  __shared__ float h1s[32 * H];
  __shared__ float sW2[4096];
  __shared__ float rel[32][3];
  __shared__ int snbr[32];
  __shared__ float sRed[4][C];
  const float* __restrict__ pb = pos + (size_t)b * Np * 3;
  if (tid < 32) {
    const int j = nbr[((size_t)b * Np + i) * 32 + tid];
    snbr[tid] = j;
    float rx = 0.f, ry = 0.f, rz = 0.f;
    if (j >= 0) {
      rx = pb[3*j]   - pb[3*i];
      ry = pb[3*j+1] - pb[3*i+1];
      rz = pb[3*j+2] - pb[3*i+2];
    }
    rel[tid][0] = rx; rel[tid][1] = ry; rel[tid][2] = rz;
  }
  __syncthreads();
  // phase B: h1[k][h] = relu(U[j][h] (+b1) + rel . Wrel[:,h]); invalid k -> 0
  for (int idx = tid; idx < 32 * H; idx += 256) {
    const int k = idx / H, h = idx - k * H;
    const int j = snbr[k];
    float v = 0.f;
    if (j >= 0) {
      float a = HASX ? U[((size_t)b * Np + j) * H + h] : b1[h];
      a += rel[k][0] * Wrel[h];
      a += rel[k][1] * Wrel[H + h];
      a += rel[k][2] * Wrel[2 * H + h];
      v = fmaxf(a, 0.f);
    }
    h1s[k * H + h] = v;
  }
  const int cc = tid & 63;
  const int kk = tid >> 6;
  float acc[8][CC];
#pragma unroll
  for (int e = 0; e < 8; e++)
#pragma unroll
    for (int q = 0; q < CC; q++) acc[e][q] = 0.f;
  // phase C: h2 = h1 @ W2, W2 staged in LDS chunks
  for (int hc = 0; hc < H; hc += HCHUNK) {
    __syncthreads();   // also guards phase-B h1s writes on first iteration
    for (int idx = tid; idx < HCHUNK * C; idx += 256) sW2[idx] = W2[(size_t)hc * C + idx];
    __syncthreads();
    for (int hh = 0; hh < HCHUNK; hh++) {
      float wv[CC];
#pragma unroll
      for (int q = 0; q < CC; q++) wv[q] = sW2[hh * C + cc + q * 64];
      const int h = hc + hh;
#pragma unroll
      for (int e = 0; e < 8; e++) {
        const float hv = h1s[(kk + e * 4) * H + h];   // wave-uniform broadcast
#pragma unroll
        for (int q = 0; q < CC; q++) acc[e][q] += hv * wv[q];
      }
    }
  }
  // masked max over k (NEG fill), +b2, relu
  float m[CC];
#pragma unroll
  for (int q = 0; q < CC; q++) m[q] = -1e9f;
#pragma unroll
  for (int e = 0; e < 8; e++) {
    if (snbr[kk + e * 4] >= 0) {
#pragma unroll
      for (int q = 0; q < CC; q++) m[q] = fmaxf(m[q], acc[e][q]);
    }
  }
#pragma unroll
  for (int q = 0; q < CC; q++) sRed[kk][cc + q * 64] = m[q];
  __syncthreads();
  if (kk == 0) {
#pragma unroll
    for (int q = 0; q < CC; q++) {
      const int c = cc + q * 64;
      const float mm = fmaxf(fmaxf(sRed[0][c], sRed[1][c]), fmaxf(sRed[2][c], sRed[3][c]));
      const float o = (mm > -5e8f) ? (mm + b2[c]) : -1e9f;  // no valid nbr -> NEG
      out[((size_t)b * Np + i) * C + c] = fmaxf(o, 0.f);    // fused relu from _forward
    }
  }
}

// ---------------- global max pool + classifier/defense heads ----------------
__global__ __launch_bounds__(256) void head_kernel(
    const float* __restrict__ x3,
    const float* __restrict__ Wc1, const float* __restrict__ bc1,
    const float* __restrict__ Wc2, const float* __restrict__ bc2,
    const float* __restrict__ Wc3, const float* __restrict__ bc3,
    const float* __restrict__ Wd1, const float* __restrict__ bd1,
    const float* __restrict__ Wd2, const float* __restrict__ bd2,
    float* __restrict__ out) {
  const int b = blockIdx.x, tid = threadIdx.x;
  __shared__ float sf[256], sh[256], sh2[256], shd[256], sl[48];
  float mx = -1e9f;
  const float* __restrict__ xb = x3 + (size_t)b * 512 * 256;
  for (int p = 0; p < 512; p++) mx = fmaxf(mx, xb[p * 256 + tid]);
  sf[tid] = mx;
  __syncthreads();
  float a = bc1[tid], ad = bd1[tid];
  for (int f = 0; f < 256; f++) {
    const float fv = sf[f];
    a  = fmaf(fv, Wc1[f * 256 + tid], a);
    ad = fmaf(fv, Wd1[f * 256 + tid], ad);
  }
  sh[tid] = fmaxf(a, 0.f);
  shd[tid] = fmaxf(ad, 0.f);
  __syncthreads();
  float a2 = bc2[tid];
  for (int f = 0; f < 256; f++) a2 = fmaf(sh[f], Wc2[f * 256 + tid], a2);
  sh2[tid] = fmaxf(a2, 0.f);
  __syncthreads();
  if (tid < 40) {
    float l = bc3[tid];
    for (int f = 0; f < 256; f++) l = fmaf(sh2[f], Wc3[f * 40 + tid], l);
    sl[tid] = l;
  }
  if (tid >= 64 && tid < 66) {
    const int q = tid - 64;
    float l = bd2[q];
    for (int f = 0; f < 256; f++) l = fmaf(shd[f], Wd2[f * 2 + q], l);
    sl[40 + q] = l;
  }
  __syncthreads();
  if (tid == 0) {
    float m0 = sl[0];
    for (int q = 1; q < 40; q++) m0 = fmaxf(m0, sl[q]);
    float s = 0.f;
    for (int q = 0; q < 40; q++) s += expf(sl[q] - m0);
    const float ls = logf(s);
    for (int q = 0; q < 40; q++) out[b * 40 + q] = sl[q] - m0 - ls;
    const float m1 = fmaxf(sl[40], sl[41]);
    const float s1 = expf(sl[40] - m1) + expf(sl[41] - m1);
    const float ls1 = logf(s1);
    out[320 + b * 2 + 0] = sl[40] - m1 - ls1;
    out[320 + b * 2 + 1] = sl[41] - m1 - ls1;
  }
}

// ---------------------------------------------------------------------------
extern "C" void kernel_launch(void* const* d_in, const int* in_sizes, int n_in,
                              void* d_out, int out_size, void* d_ws, size_t ws_size,
                              hipStream_t stream) {
  (void)in_sizes; (void)n_in; (void)out_size; (void)ws_size;
  const float* pos = (const float*)d_in[0];
  const float* W1a = (const float*)d_in[1];  const float* b1a = (const float*)d_in[2];
  const float* W1b = (const float*)d_in[3];  const float* b1b = (const float*)d_in[4];
  const float* W2a = (const float*)d_in[5];  const float* b2a = (const float*)d_in[6];
  const float* W2b = (const float*)d_in[7];  const float* b2b = (const float*)d_in[8];
  const float* W3a = (const float*)d_in[9];  const float* b3a = (const float*)d_in[10];
  const float* W3b = (const float*)d_in[11]; const float* b3b = (const float*)d_in[12];
  const float* Wc1 = (const float*)d_in[13]; const float* bc1 = (const float*)d_in[14];
  const float* Wc2 = (const float*)d_in[15]; const float* bc2 = (const float*)d_in[16];
  const float* Wc3 = (const float*)d_in[17]; const float* bc3 = (const float*)d_in[18];
  const float* Wd1 = (const float*)d_in[19]; const float* bd1 = (const float*)d_in[20];
  const float* Wd2 = (const float*)d_in[21]; const float* bd2 = (const float*)d_in[22];
  float* out = (float*)d_out;

  char* w = (char*)d_ws;
  auto alloc = [&](size_t bytes) -> void* {
    void* p = (void*)w;
    w += (bytes + 255) & ~(size_t)255;
    return p;
  };
  int*   nbr1 = (int*)  alloc((size_t)NB*4096*32*4);
  float* x1   = (float*)alloc((size_t)NB*4096*64*4);
  int*   fi1  = (int*)  alloc((size_t)NB*2048*4);
  float* pos2 = (float*)alloc((size_t)NB*2048*3*4);
  float* x1g  = (float*)alloc((size_t)NB*2048*64*4);
  float* U2   = (float*)alloc((size_t)NB*2048*128*4);
  int*   nbr2 = (int*)  alloc((size_t)NB*2048*32*4);
  float* x2   = (float*)alloc((size_t)NB*2048*128*4);
  int*   fi2  = (int*)  alloc((size_t)NB*512*4);
  float* pos3 = (float*)alloc((size_t)NB*512*3*4);
  float* x2g  = (float*)alloc((size_t)NB*512*128*4);
  float* U3   = (float*)alloc((size_t)NB*512*256*4);
  int*   nbr3 = (int*)  alloc((size_t)NB*512*32*4);
  float* x3   = (float*)alloc((size_t)NB*512*256*4);

  // stage 1 (N=4096, r=0.2)
  knn_kernel<4096><<<dim3(4096, NB), 256, 0, stream>>>(pos, 0.2 * 0.2, nbr1);
  conv_kernel<64, 64, false><<<dim3(4096, NB), 256, 0, stream>>>(
      pos, 4096, nbr1, nullptr, W1a, b1a, W1b, b1b, x1);
  fps_kernel<4096, 2048><<<NB, 256, 0, stream>>>(pos, fi1);
  gather_kernel<64><<<NB * 2048, 64, 0, stream>>>(x1, pos, fi1, 4096, 2048, x1g, pos2);

  // stage 2 (N=2048, r=0.4)
  knn_kernel<2048><<<dim3(2048, NB), 256, 0, stream>>>(pos2, 0.4 * 0.4, nbr2);
  preproj_kernel<64, 128><<<NB * 2048, 128, 0, stream>>>(x1g, W2a, b2a, U2);
  conv_kernel<128, 128, true><<<dim3(2048, NB), 256, 0, stream>>>(
      pos2, 2048, nbr2, U2, W2a + (size_t)64 * 128, b2a, W2b, b2b, x2);
  fps_kernel<2048, 512><<<NB, 256, 0, stream>>>(pos2, fi2);
  gather_kernel<128><<<NB * 512, 128, 0, stream>>>(x2, pos2, fi2, 2048, 512, x2g, pos3);

  // stage 3 (N=512, r=1.0)
  knn_kernel<512><<<dim3(512, NB), 256, 0, stream>>>(pos3, 1.0, nbr3);
  preproj_kernel<128, 256><<<NB * 512, 256, 0, stream>>>(x2g, W3a, b3a, U3);
  conv_kernel<256, 256, true><<<dim3(512, NB), 256, 0, stream>>>(
      pos3, 512, nbr3, U3, W3a + (size_t)128 * 256, b3a, W3b, b3b, x3);

  // heads
  head_kernel<<<NB, 256, 0, stream>>>(x3, Wc1, bc1, Wc2, bc2, Wc3, bc3,
                                      Wd1, bd1, Wd2, bd2, out);
}

// Round 5
// 4048.138 us; speedup vs baseline: 1.2837x; 1.2837x over previous
//
#include <hip/hip_runtime.h>

// ---------------------------------------------------------------------------
// PointNet++ (defense variant) forward on MI355X.
// B=8, N=4096 -> 2048 -> 512, K=32 neighbors. Geometry is EXACT: positions are
// multiples of 2^-23, so i32 coords (x*2^23) give d2 = dx^2+dy^2+dz^2 exactly
// in i64 (<2^50) — selection/FPS ranking matches an np-f64 reference exactly.
// R5: FPS — amdgpu_waves_per_eu(1,1) to stop the allocator demoting the
// per-thread point state (R4: VGPR=68 < the ~80-reg state ⇒ per-iter reloads),
// + packed u64 keys (d2<<12 | 4095-j): whole reduction is a u64 max.
// ---------------------------------------------------------------------------

#define NB 8

__device__ __forceinline__ unsigned obits(float f) {
  unsigned u = __float_as_uint(f);
  return (u & 0x80000000u) ? ~u : (u | 0x80000000u);
}

static constexpr int CAND = 1024;

// ---------------- radius-KNN: exact top-32 by (d2, idx) lex order -----------
template<int N>
__global__ __launch_bounds__(256) void knn_kernel(const float* __restrict__ pos,
                                                  double rr, int* __restrict__ nbr) {
  const int i = blockIdx.x, b = blockIdx.y;
  const int tid = threadIdx.x;
  const float* __restrict__ pb = pos + (size_t)b * N * 3;
  __shared__ double d2s[N];
  __shared__ unsigned hist[2048];
  __shared__ unsigned scanBuf[256];
  __shared__ int candIdx[CAND];
  __shared__ int candCnt;
  __shared__ int sBinT;

  const double xi = pb[3*i], yi = pb[3*i+1], zi = pb[3*i+2];
  const double si = (xi*xi + yi*yi) + zi*zi;
  for (int t = tid; t < 2048; t += 256) hist[t] = 0u;
  if (tid == 0) candCnt = 0;
  __syncthreads();
  for (int j = tid; j < N; j += 256) {
    double xj = pb[3*j], yj = pb[3*j+1], zj = pb[3*j+2];
    double sj = (xj*xj + yj*yj) + zj*zj;
    double dt = (xi*xj + yi*yj) + zi*zj;
    double d2 = (si + sj) - 2.0*dt;          // exact in f64 (see header note)
    if (j == i) d2 += 1e9;                   // self-exclusion as in reference
    d2s[j] = d2;
    atomicAdd(&hist[obits((float)d2) >> 21], 1u);
  }
  __syncthreads();
  // find smallest bin T with cumulative count >= 32
  unsigned lsum = 0;
  const int base = tid * 8;
#pragma unroll
  for (int q = 0; q < 8; q++) lsum += hist[base + q];
  scanBuf[tid] = lsum;
  __syncthreads();
  for (int ofs = 1; ofs < 256; ofs <<= 1) {
    unsigned v = scanBuf[tid];
    unsigned addv = (tid >= ofs) ? scanBuf[tid - ofs] : 0u;
    __syncthreads();
    scanBuf[tid] = v + addv;
    __syncthreads();
  }
  const unsigned incl = scanBuf[tid], excl = incl - lsum;
  if (excl < 32u && incl >= 32u) {
    unsigned c = excl;
    for (int q = 0; q < 8; q++) {
      c += hist[base + q];
      if (c >= 32u) { sBinT = base + q; break; }
    }
  }
  __syncthreads();
  const int binT = sBinT;
  for (int j = tid; j < N; j += 256) {
    if ((int)(obits((float)d2s[j]) >> 21) <= binT) {
      int p = atomicAdd(&candCnt, 1);
      if (p < CAND) candIdx[p] = j;
    }
  }
  __syncthreads();
  const int M = min(candCnt, CAND);   // M >= 32 by construction; overflow ~impossible
  int* __restrict__ outp = nbr + ((size_t)b * N + i) * 32;
  for (int c = tid; c < M; c += 256) {
    const int j = candIdx[c];
    const double d = d2s[j];
    int rank = 0;
    for (int e = 0; e < M; e++) {
      const int j2 = candIdx[e];
      const double de = d2s[j2];
      rank += (de < d || (de == d && j2 < j)) ? 1 : 0;
    }
    if (rank < 32) outp[rank] = (d <= rr) ? j : -1;  // fold radius-validity into -1
  }
}

// ---------------- farthest point sampling (exact integer, deterministic) ----
// 256 threads (4 waves, 1/SIMD). waves_per_eu(1,1): allocator targets exactly
// 1 wave/EU so the ~130-reg point state stays in registers (R4's VGPR=68
// proved launch_bounds alone doesn't stop the occupancy heuristic).
// Coords i32 (x*2^23, exact); mind held as packed u64 keys:
//   key = (d2 << 12) | (4095 - j)   ⇒  max key == (max d2, tie -> min j).
template<int N, int NOUT>
__global__ __attribute__((amdgpu_waves_per_eu(1, 1)))
__launch_bounds__(256, 1) void fps_kernel(const float* __restrict__ pos,
                                          int* __restrict__ fi) {
  const int b = blockIdx.x;
  const float* __restrict__ pb = pos + (size_t)b * N * 3;
  constexpr int P = N / 256;
  const int tid = threadIdx.x;
  const int wid = tid >> 6, lane = tid & 63;
  int ix[P], iy[P], iz[P];
  unsigned long long mind[P];
  __shared__ int sPosI[N][3];
  __shared__ unsigned long long sKey[2][4];
  // stage integer positions into LDS (one-time, read-only afterwards)
  for (int t = tid; t < N; t += 256) {
    sPosI[t][0] = (int)(pb[3*t]   * 8388608.f);   // exact: x is a 2^-23 multiple
    sPosI[t][1] = (int)(pb[3*t+1] * 8388608.f);
    sPosI[t][2] = (int)(pb[3*t+2] * 8388608.f);
  }
  __syncthreads();
  const int x0 = sPosI[0][0], y0 = sPosI[0][1], z0 = sPosI[0][2];
  const int invBase = 4095 - tid * P;
  unsigned long long bv;
  {
    unsigned long long tv[P];
#pragma unroll
    for (int e = 0; e < P; e++) {
      const int j = tid * P + e;
      const int x = sPosI[j][0], y = sPosI[j][1], z = sPosI[j][2];
      ix[e] = x; iy[e] = y; iz[e] = z;
      const long long dx = x - x0, dy = y - y0, dz = z - z0;
      const unsigned long long d2 =
          (unsigned long long)(dx * dx + dy * dy + dz * dz);   // exact, < 2^50
      const unsigned long long k = (d2 << 12) | (unsigned)(invBase - e);
      mind[e] = k; tv[e] = k;
    }
#pragma unroll
    for (int s = 1; s < P; s <<= 1)
#pragma unroll
      for (int e = 0; e + s < P; e += 2 * s)
        if (tv[e + s] > tv[e]) tv[e] = tv[e + s];
    bv = tv[0];
  }
  if (tid == 0) fi[(size_t)b * NOUT] = 0;
  for (int t = 1; t < NOUT; t++) {
    // wave-level u64-max butterfly (ties impossible: idx bits are unique)
    unsigned long long v = bv;
#pragma unroll
    for (int o = 32; o; o >>= 1) {
      const unsigned long long ov = __shfl_down(v, o);
      v = (ov > v) ? ov : v;
    }
    const int pp = t & 1;
    if (lane == 0) sKey[pp][wid] = v;
    __syncthreads();   // the only barrier per iteration (partials double-buffered)
    // all threads redundantly reduce the 4 wave partials (2-level tree)
    unsigned long long k0 = sKey[pp][0], k1 = sKey[pp][1],
                       k2 = sKey[pp][2], k3 = sKey[pp][3];
    k0 = (k1 > k0) ? k1 : k0;
    k2 = (k3 > k2) ? k3 : k2;
    k0 = (k2 > k0) ? k2 : k0;
    const int ii = 4095 - (int)(k0 & 0xFFFull);   // global winner index
    if (tid == 0) fi[(size_t)b * NOUT + t] = ii;
    // winner coords: conflict-free same-address LDS broadcast
    const int wx = sPosI[ii][0], wy = sPosI[ii][1], wz = sPosI[ii][2];
    // fused update + pairwise-tree rescan (keys only; identity rides low bits)
    unsigned long long tv[P];
#pragma unroll
    for (int e = 0; e < P; e++) {
      const long long dx = ix[e] - wx, dy = iy[e] - wy, dz = iz[e] - wz;
      const unsigned long long nd =
          (unsigned long long)(dx * dx + dy * dy + dz * dz);
      const unsigned long long nk = (nd << 12) | (unsigned)(invBase - e);
      unsigned long long mk = mind[e];
      mk = (nk < mk) ? nk : mk;
      mind[e] = mk;
      tv[e] = mk;
    }
#pragma unroll
    for (int s = 1; s < P; s <<= 1)
#pragma unroll
      for (int e = 0; e + s < P; e += 2 * s)
        if (tv[e + s] > tv[e]) tv[e] = tv[e + s];
    bv = tv[0];
  }
}

// ---------------- gather rows by fps indices --------------------------------
template<int CIN>
__global__ void gather_kernel(const float* __restrict__ X, const float* __restrict__ pos,
                              const int* __restrict__ fi, int N, int M,
                              float* __restrict__ Xg, float* __restrict__ posg) {
  const int row = blockIdx.x;
  const int b = row / M;
  const int tid = threadIdx.x;
  const int j = fi[row];
  if (tid < CIN) Xg[(size_t)row * CIN + tid] = X[((size_t)b * N + j) * CIN + tid];
  if (tid < 3) posg[(size_t)row * 3 + tid] = pos[((size_t)b * N + j) * 3 + tid];
}

// ---------------- per-source-point projection U = x*W1[:CIN] + b1 -----------
template<int CIN, int H>
__global__ void preproj_kernel(const float* __restrict__ X, const float* __restrict__ W,
                               const float* __restrict__ bias, float* __restrict__ U) {
  const int row = blockIdx.x;
  const int tid = threadIdx.x;
  __shared__ float sx[CIN];
  if (tid < CIN) sx[tid] = X[(size_t)row * CIN + tid];
  __syncthreads();
  float a = bias[tid];
  for (int f = 0; f < CIN; f++) a = fmaf(sx[f], W[f * H + tid], a);
  U[(size_t)row * H + tid] = a;
}

// ---------------- fused PointConv (edge MLP + masked max + relu) ------------
// threads = 256 = 4 k-groups x 64 c-lanes; each thread: 8 k's x (C/64) c's.
template<int H, int C, bool HASX>
__global__ __launch_bounds__(256) void conv_kernel(
    const float* __restrict__ pos, int Np,
    const int* __restrict__ nbr,
    const float* __restrict__ U,        // [B*Np, H] (x*W1x + b1) or nullptr
    const float* __restrict__ Wrel,     // rel rows of W1: [3][H]
    const float* __restrict__ b1,       // used only when !HASX
    const float* __restrict__ W2, const float* __restrict__ b2,
    float* __restrict__ out) {
  constexpr int HCHUNK = 4096 / C;
  constexpr int CC = C / 64;
  const int i = blockIdx.x, b = blockIdx.y;
  const int tid = threadIdx.x;
  __shared__ float h1s[32 * H];
  __shared__ float sW2[4096];
  __shared__ float rel[32][3];
  __shared__ int snbr[32];
  __shared__ float sRed[4][C];
  const float* __restrict__ pb = pos + (size_t)b * Np * 3;
  if (tid < 32) {
    const int j = nbr[((size_t)b * Np + i) * 32 + tid];
    snbr[tid] = j;
    float rx = 0.f, ry = 0.f, rz = 0.f;
    if (j >= 0) {
      rx = pb[3*j]   - pb[3*i];
      ry = pb[3*j+1] - pb[3*i+1];
      rz = pb[3*j+2] - pb[3*i+2];
    }
    rel[tid][0] = rx; rel[tid][1] = ry; rel[tid][2] = rz;
  }
  __syncthreads();
  // phase B: h1[k][h] = relu(U[j][h] (+b1) + rel . Wrel[:,h]); invalid k -> 0
  for (int idx = tid; idx < 32 * H; idx += 256) {
    const int k = idx / H, h = idx - k * H;
    const int j = snbr[k];
    float v = 0.f;
    if (j >= 0) {
      float a = HASX ? U[((size_t)b * Np + j) * H + h] : b1[h];
      a += rel[k][0] * Wrel[h];
      a += rel[k][1] * Wrel[H + h];
      a += rel[k][2] * Wrel[2 * H + h];
      v = fmaxf(a, 0.f);
    }
    h1s[k * H + h] = v;
  }
  const int cc = tid & 63;
  const int kk = tid >> 6;
  float acc[8][CC];
#pragma unroll
  for (int e = 0; e < 8; e++)
#pragma unroll
    for (int q = 0; q < CC; q++) acc[e][q] = 0.f;
  // phase C: h2 = h1 @ W2, W2 staged in LDS chunks
  for (int hc = 0; hc < H; hc += HCHUNK) {
    __syncthreads();   // also guards phase-B h1s writes on first iteration
    for (int idx = tid; idx < HCHUNK * C; idx += 256) sW2[idx] = W2[(size_t)hc * C + idx];
    __syncthreads();
    for (int hh = 0; hh < HCHUNK; hh++) {
      float wv[CC];
#pragma unroll
      for (int q = 0; q < CC; q++) wv[q] = sW2[hh * C + cc + q * 64];
      const int h = hc + hh;
#pragma unroll
      for (int e = 0; e < 8; e++) {
        const float hv = h1s[(kk + e * 4) * H + h];   // wave-uniform broadcast
#pragma unroll
        for (int q = 0; q < CC; q++) acc[e][q] += hv * wv[q];
      }
    }
  }
  // masked max over k (NEG fill), +b2, relu
  float m[CC];
#pragma unroll
  for (int q = 0; q < CC; q++) m[q] = -1e9f;
#pragma unroll
  for (int e = 0; e < 8; e++) {
    if (snbr[kk + e * 4] >= 0) {
#pragma unroll
      for (int q = 0; q < CC; q++) m[q] = fmaxf(m[q], acc[e][q]);
    }
  }
#pragma unroll
  for (int q = 0; q < CC; q++) sRed[kk][cc + q * 64] = m[q];
  __syncthreads();
  if (kk == 0) {
#pragma unroll
    for (int q = 0; q < CC; q++) {
      const int c = cc + q * 64;
      const float mm = fmaxf(fmaxf(sRed[0][c], sRed[1][c]), fmaxf(sRed[2][c], sRed[3][c]));
      const float o = (mm > -5e8f) ? (mm + b2[c]) : -1e9f;  // no valid nbr -> NEG
      out[((size_t)b * Np + i) * C + c] = fmaxf(o, 0.f);    // fused relu from _forward
    }
  }
}

// ---------------- global max pool + classifier/defense heads ----------------
__global__ __launch_bounds__(256) void head_kernel(
    const float* __restrict__ x3,
    const float* __restrict__ Wc1, const float* __restrict__ bc1,
    const float* __restrict__ Wc2, const float* __restrict__ bc2,
    const float* __restrict__ Wc3, const float* __restrict__ bc3,
    const float* __restrict__ Wd1, const float* __restrict__ bd1,
    const float* __restrict__ Wd2, const float* __restrict__ bd2,
    float* __restrict__ out) {
  const int b = blockIdx.x, tid = threadIdx.x;
  __shared__ float sf[256], sh[256], sh2[256], shd[256], sl[48];
  float mx = -1e9f;
  const float* __restrict__ xb = x3 + (size_t)b * 512 * 256;
  for (int p = 0; p < 512; p++) mx = fmaxf(mx, xb[p * 256 + tid]);
  sf[tid] = mx;
  __syncthreads();
  float a = bc1[tid], ad = bd1[tid];
  for (int f = 0; f < 256; f++) {
    const float fv = sf[f];
    a  = fmaf(fv, Wc1[f * 256 + tid], a);
    ad = fmaf(fv, Wd1[f * 256 + tid], ad);
  }
  sh[tid] = fmaxf(a, 0.f);
  shd[tid] = fmaxf(ad, 0.f);
  __syncthreads();
  float a2 = bc2[tid];
  for (int f = 0; f < 256; f++) a2 = fmaf(sh[f], Wc2[f * 256 + tid], a2);
  sh2[tid] = fmaxf(a2, 0.f);
  __syncthreads();
  if (tid < 40) {
    float l = bc3[tid];
    for (int f = 0; f < 256; f++) l = fmaf(sh2[f], Wc3[f * 40 + tid], l);
    sl[tid] = l;
  }
  if (tid >= 64 && tid < 66) {
    const int q = tid - 64;
    float l = bd2[q];
    for (int f = 0; f < 256; f++) l = fmaf(shd[f], Wd2[f * 2 + q], l);
    sl[40 + q] = l;
  }
  __syncthreads();
  if (tid == 0) {
    float m0 = sl[0];
    for (int q = 1; q < 40; q++) m0 = fmaxf(m0, sl[q]);
    float s = 0.f;
    for (int q = 0; q < 40; q++) s += expf(sl[q] - m0);
    const float ls = logf(s);
    for (int q = 0; q < 40; q++) out[b * 40 + q] = sl[q] - m0 - ls;
    const float m1 = fmaxf(sl[40], sl[41]);
    const float s1 = expf(sl[40] - m1) + expf(sl[41] - m1);
    const float ls1 = logf(s1);
    out[320 + b * 2 + 0] = sl[40] - m1 - ls1;
    out[320 + b * 2 + 1] = sl[41] - m1 - ls1;
  }
}

// ---------------------------------------------------------------------------
extern "C" void kernel_launch(void* const* d_in, const int* in_sizes, int n_in,
                              void* d_out, int out_size, void* d_ws, size_t ws_size,
                              hipStream_t stream) {
  (void)in_sizes; (void)n_in; (void)out_size; (void)ws_size;
  const float* pos = (const float*)d_in[0];
  const float* W1a = (const float*)d_in[1];  const float* b1a = (const float*)d_in[2];
  const float* W1b = (const float*)d_in[3];  const float* b1b = (const float*)d_in[4];
  const float* W2a = (const float*)d_in[5];  const float* b2a = (const float*)d_in[6];
  const float* W2b = (const float*)d_in[7];  const float* b2b = (const float*)d_in[8];
  const float* W3a = (const float*)d_in[9];  const float* b3a = (const float*)d_in[10];
  const float* W3b = (const float*)d_in[11]; const float* b3b = (const float*)d_in[12];
  const float* Wc1 = (const float*)d_in[13]; const float* bc1 = (const float*)d_in[14];
  const float* Wc2 = (const float*)d_in[15]; const float* bc2 = (const float*)d_in[16];
  const float* Wc3 = (const float*)d_in[17]; const float* bc3 = (const float*)d_in[18];
  const float* Wd1 = (const float*)d_in[19]; const float* bd1 = (const float*)d_in[20];
  const float* Wd2 = (const float*)d_in[21]; const float* bd2 = (const float*)d_in[22];
  float* out = (float*)d_out;

  char* w = (char*)d_ws;
  auto alloc = [&](size_t bytes) -> void* {
    void* p = (void*)w;
    w += (bytes + 255) & ~(size_t)255;
    return p;
  };
  int*   nbr1 = (int*)  alloc((size_t)NB*4096*32*4);
  float* x1   = (float*)alloc((size_t)NB*4096*64*4);
  int*   fi1  = (int*)  alloc((size_t)NB*2048*4);
  float* pos2 = (float*)alloc((size_t)NB*2048*3*4);
  float* x1g  = (float*)alloc((size_t)NB*2048*64*4);
  float* U2   = (float*)alloc((size_t)NB*2048*128*4);
  int*   nbr2 = (int*)  alloc((size_t)NB*2048*32*4);
  float* x2   = (float*)alloc((size_t)NB*2048*128*4);
  int*   fi2  = (int*)  alloc((size_t)NB*512*4);
  float* pos3 = (float*)alloc((size_t)NB*512*3*4);
  float* x2g  = (float*)alloc((size_t)NB*512*128*4);
  float* U3   = (float*)alloc((size_t)NB*512*256*4);
  int*   nbr3 = (int*)  alloc((size_t)NB*512*32*4);
  float* x3   = (float*)alloc((size_t)NB*512*256*4);

  // stage 1 (N=4096, r=0.2)
  knn_kernel<4096><<<dim3(4096, NB), 256, 0, stream>>>(pos, 0.2 * 0.2, nbr1);
  conv_kernel<64, 64, false><<<dim3(4096, NB), 256, 0, stream>>>(
      pos, 4096, nbr1, nullptr, W1a, b1a, W1b, b1b, x1);
  fps_kernel<4096, 2048><<<NB, 256, 0, stream>>>(pos, fi1);
  gather_kernel<64><<<NB * 2048, 64, 0, stream>>>(x1, pos, fi1, 4096, 2048, x1g, pos2);

  // stage 2 (N=2048, r=0.4)
  knn_kernel<2048><<<dim3(2048, NB), 256, 0, stream>>>(pos2, 0.4 * 0.4, nbr2);
  preproj_kernel<64, 128><<<NB * 2048, 128, 0, stream>>>(x1g, W2a, b2a, U2);
  conv_kernel<128, 128, true><<<dim3(2048, NB), 256, 0, stream>>>(
      pos2, 2048, nbr2, U2, W2a + (size_t)64 * 128, b2a, W2b, b2b, x2);
  fps_kernel<2048, 512><<<NB, 256, 0, stream>>>(pos2, fi2);
  gather_kernel<128><<<NB * 512, 128, 0, stream>>>(x2, pos2, fi2, 2048, 512, x2g, pos3);

  // stage 3 (N=512, r=1.0)
  knn_kernel<512><<<dim3(512, NB), 256, 0, stream>>>(pos3, 1.0, nbr3);
  preproj_kernel<128, 256><<<NB * 512, 256, 0, stream>>>(x2g, W3a, b3a, U3);
  conv_kernel<256, 256, true><<<dim3(512, NB), 256, 0, stream>>>(
      pos3, 512, nbr3, U3, W3a + (size_t)128 * 256, b3a, W3b, b3b, x3);

  // heads
  head_kernel<<<NB, 256, 0, stream>>>(x3, Wc1, bc1, Wc2, bc2, Wc3, bc3,
                                      Wd1, bd1, Wd2, bd2, out);
}

// Round 6
// 3712.809 us; speedup vs baseline: 1.3997x; 1.0903x over previous
//
#include <hip/hip_runtime.h>

// ---------------------------------------------------------------------------
// PointNet++ (defense variant) forward on MI355X.
// B=8, N=4096 -> 2048 -> 512, K=32 neighbors. Geometry is EXACT: positions are
// multiples of 2^-23, so i32 coords (x*2^23) give d2 = dx^2+dy^2+dz^2 exactly
// in i64 (<2^48) — selection/FPS ranking matches an np-f64 reference exactly.
// R6: FPS serial-loop latency — (1) DPP-based wave u64-max (~70 cyc vs ~330
// for 6x ds_bpermute shfl), (2) fi buffered in LDS (in-loop global store made
// every __syncthreads drain vmcnt(0) -> ~200 cyc/iter), (3) int4 coords
// (single ds_read_b128 for the winner broadcast).
// ---------------------------------------------------------------------------

#define NB 8

__device__ __forceinline__ unsigned obits(float f) {
  unsigned u = __float_as_uint(f);
  return (u & 0x80000000u) ? ~u : (u | 0x80000000u);
}

static constexpr int CAND = 1024;

// ---------------- radius-KNN: exact top-32 by (d2, idx) lex order -----------
template<int N>
__global__ __launch_bounds__(256) void knn_kernel(const float* __restrict__ pos,
                                                  double rr, int* __restrict__ nbr) {
  const int i = blockIdx.x, b = blockIdx.y;
  const int tid = threadIdx.x;
  const float* __restrict__ pb = pos + (size_t)b * N * 3;
  __shared__ double d2s[N];
  __shared__ unsigned hist[2048];
  __shared__ unsigned scanBuf[256];
  __shared__ int candIdx[CAND];
  __shared__ int candCnt;
  __shared__ int sBinT;

  const double xi = pb[3*i], yi = pb[3*i+1], zi = pb[3*i+2];
  const double si = (xi*xi + yi*yi) + zi*zi;
  for (int t = tid; t < 2048; t += 256) hist[t] = 0u;
  if (tid == 0) candCnt = 0;
  __syncthreads();
  for (int j = tid; j < N; j += 256) {
    double xj = pb[3*j], yj = pb[3*j+1], zj = pb[3*j+2];
    double sj = (xj*xj + yj*yj) + zj*zj;
    double dt = (xi*xj + yi*yj) + zi*zj;
    double d2 = (si + sj) - 2.0*dt;          // exact in f64 (see header note)
    if (j == i) d2 += 1e9;                   // self-exclusion as in reference
    d2s[j] = d2;
    atomicAdd(&hist[obits((float)d2) >> 21], 1u);
  }
  __syncthreads();
  // find smallest bin T with cumulative count >= 32
  unsigned lsum = 0;
  const int base = tid * 8;
#pragma unroll
  for (int q = 0; q < 8; q++) lsum += hist[base + q];
  scanBuf[tid] = lsum;
  __syncthreads();
  for (int ofs = 1; ofs < 256; ofs <<= 1) {
    unsigned v = scanBuf[tid];
    unsigned addv = (tid >= ofs) ? scanBuf[tid - ofs] : 0u;
    __syncthreads();
    scanBuf[tid] = v + addv;
    __syncthreads();
  }
  const unsigned incl = scanBuf[tid], excl = incl - lsum;
  if (excl < 32u && incl >= 32u) {
    unsigned c = excl;
    for (int q = 0; q < 8; q++) {
      c += hist[base + q];
      if (c >= 32u) { sBinT = base + q; break; }
    }
  }
  __syncthreads();
  const int binT = sBinT;
  for (int j = tid; j < N; j += 256) {
    if ((int)(obits((float)d2s[j]) >> 21) <= binT) {
      int p = atomicAdd(&candCnt, 1);
      if (p < CAND) candIdx[p] = j;
    }
  }
  __syncthreads();
  const int M = min(candCnt, CAND);   // M >= 32 by construction; overflow ~impossible
  int* __restrict__ outp = nbr + ((size_t)b * N + i) * 32;
  for (int c = tid; c < M; c += 256) {
    const int j = candIdx[c];
    const double d = d2s[j];
    int rank = 0;
    for (int e = 0; e < M; e++) {
      const int j2 = candIdx[e];
      const double de = d2s[j2];
      rank += (de < d || (de == d && j2 < j)) ? 1 : 0;
    }
    if (rank < 32) outp[rank] = (d <= rr) ? j : -1;  // fold radius-validity into -1
  }
}

// ---------------- DPP u64-max step (VALU cross-lane, no LDS pipe) -----------
template<int CTRL>
__device__ __forceinline__ unsigned long long dpp_max_step(unsigned long long v) {
  const int lo = (int)(unsigned)(v & 0xffffffffull);
  const int hi = (int)(unsigned)(v >> 32);
  const unsigned nlo = (unsigned)__builtin_amdgcn_update_dpp(lo, lo, CTRL, 0xf, 0xf, false);
  const unsigned nhi = (unsigned)__builtin_amdgcn_update_dpp(hi, hi, CTRL, 0xf, 0xf, false);
  const unsigned long long nv = ((unsigned long long)nhi << 32) | nlo;
  return (nv > v) ? nv : v;
}

// ---------------- farthest point sampling (exact integer, deterministic) ----
// 256 threads (4 waves, 1/SIMD). waves_per_eu(1,1) keeps the ~130-reg point
// state in registers (R5-verified). Coords i32 (x*2^23, exact); mind as
// packed u64 keys: key = (d2 << 12) | (4095 - j) => max key == (max d2, min j).
// Wave reduce: DPP row_shr 1/2/4/8 + row_bcast15/31 -> lane 63 holds wave max.
template<int N, int NOUT>
__global__ __attribute__((amdgpu_waves_per_eu(1, 1)))
__launch_bounds__(256, 1) void fps_kernel(const float* __restrict__ pos,
                                          int* __restrict__ fi) {
  const int b = blockIdx.x;
  const float* __restrict__ pb = pos + (size_t)b * N * 3;
  constexpr int P = N / 256;
  const int tid = threadIdx.x;
  const int wid = tid >> 6, lane = tid & 63;
  int ix[P], iy[P], iz[P];
  unsigned long long mind[P];
  __shared__ int4 sPosI[N];
  __shared__ unsigned long long sKey[2][4];
  __shared__ int sfi[NOUT];
  // stage integer positions into LDS (one-time, read-only afterwards)
  for (int t = tid; t < N; t += 256) {
    sPosI[t] = make_int4((int)(pb[3*t]   * 8388608.f),   // exact: 2^-23 multiples
                         (int)(pb[3*t+1] * 8388608.f),
                         (int)(pb[3*t+2] * 8388608.f), 0);
  }
  __syncthreads();
  const int x0 = sPosI[0].x, y0 = sPosI[0].y, z0 = sPosI[0].z;
  const int invBase = 4095 - tid * P;
  unsigned long long bv;
  {
    unsigned long long tv[P];
#pragma unroll
    for (int e = 0; e < P; e++) {
      const int j = tid * P + e;
      const int4 p4 = sPosI[j];
      ix[e] = p4.x; iy[e] = p4.y; iz[e] = p4.z;
      const long long dx = p4.x - x0, dy = p4.y - y0, dz = p4.z - z0;
      const unsigned long long d2 =
          (unsigned long long)(dx * dx + dy * dy + dz * dz);   // exact, < 2^48
      const unsigned long long k = (d2 << 12) | (unsigned)(invBase - e);
      mind[e] = k; tv[e] = k;
    }
#pragma unroll
    for (int s = 1; s < P; s <<= 1)
#pragma unroll
      for (int e = 0; e + s < P; e += 2 * s)
        if (tv[e + s] > tv[e]) tv[e] = tv[e + s];
    bv = tv[0];
  }
  if (tid == 0) sfi[0] = 0;
  for (int t = 1; t < NOUT; t++) {
    // wave u64-max via DPP (row reduce then cross-row bcasts; result in lane 63)
    unsigned long long v = bv;
    v = dpp_max_step<0x111>(v);   // row_shr:1
    v = dpp_max_step<0x112>(v);   // row_shr:2
    v = dpp_max_step<0x114>(v);   // row_shr:4
    v = dpp_max_step<0x118>(v);   // row_shr:8
    v = dpp_max_step<0x142>(v);   // row_bcast:15
    v = dpp_max_step<0x143>(v);   // row_bcast:31
    const int pp = t & 1;
    if (lane == 63) sKey[pp][wid] = v;
    __syncthreads();   // the only barrier per iteration; drains LDS only (no
                       // global stores in the loop -> no vmcnt(0) stall)
    // all threads redundantly reduce the 4 wave partials (2-level tree)
    unsigned long long k0 = sKey[pp][0], k1 = sKey[pp][1],
                       k2 = sKey[pp][2], k3 = sKey[pp][3];
    k0 = (k1 > k0) ? k1 : k0;
    k2 = (k3 > k2) ? k3 : k2;
    k0 = (k2 > k0) ? k2 : k0;
    const int ii = 4095 - (int)(k0 & 0xFFFull);   // global winner index
    if (tid == 0) sfi[t] = ii;
    // winner coords: single ds_read_b128, conflict-free same-address broadcast
    const int4 wc = sPosI[ii];
    // fused update + pairwise-tree rescan (keys only; identity rides low bits)
    unsigned long long tv[P];
#pragma unroll
    for (int e = 0; e < P; e++) {
      const long long dx = ix[e] - wc.x, dy = iy[e] - wc.y, dz = iz[e] - wc.z;
      const unsigned long long nd =
          (unsigned long long)(dx * dx + dy * dy + dz * dz);
      const unsigned long long nk = (nd << 12) | (unsigned)(invBase - e);
      unsigned long long mk = mind[e];
      mk = (nk < mk) ? nk : mk;
      mind[e] = mk;
      tv[e] = mk;
    }
#pragma unroll
    for (int s = 1; s < P; s <<= 1)
#pragma unroll
      for (int e = 0; e + s < P; e += 2 * s)
        if (tv[e + s] > tv[e]) tv[e] = tv[e + s];
    bv = tv[0];
  }
  // flush the index buffer to global (coalesced, once)
  __syncthreads();
  for (int t = tid; t < NOUT; t += 256) fi[(size_t)b * NOUT + t] = sfi[t];
}

// ---------------- gather rows by fps indices --------------------------------
template<int CIN>
__global__ void gather_kernel(const float* __restrict__ X, const float* __restrict__ pos,
                              const int* __restrict__ fi, int N, int M,
                              float* __restrict__ Xg, float* __restrict__ posg) {
  const int row = blockIdx.x;
  const int b = row / M;
  const int tid = threadIdx.x;
  const int j = fi[row];
  if (tid < CIN) Xg[(size_t)row * CIN + tid] = X[((size_t)b * N + j) * CIN + tid];
  if (tid < 3) posg[(size_t)row * 3 + tid] = pos[((size_t)b * N + j) * 3 + tid];
}

// ---------------- per-source-point projection U = x*W1[:CIN] + b1 -----------
template<int CIN, int H>
__global__ void preproj_kernel(const float* __restrict__ X, const float* __restrict__ W,
                               const float* __restrict__ bias, float* __restrict__ U) {
  const int row = blockIdx.x;
  const int tid = threadIdx.x;
  __shared__ float sx[CIN];
  if (tid < CIN) sx[tid] = X[(size_t)row * CIN + tid];
  __syncthreads();
  float a = bias[tid];
  for (int f = 0; f < CIN; f++) a = fmaf(sx[f], W[f * H + tid], a);
  U[(size_t)row * H + tid] = a;
}

// ---------------- fused PointConv (edge MLP + masked max + relu) ------------
// threads = 256 = 4 k-groups x 64 c-lanes; each thread: 8 k's x (C/64) c's.
template<int H, int C, bool HASX>
__global__ __launch_bounds__(256) void conv_kernel(
    const float* __restrict__ pos, int Np,
    const int* __restrict__ nbr,
    const float* __restrict__ U,        // [B*Np, H] (x*W1x + b1) or nullptr
    const float* __restrict__ Wrel,     // rel rows of W1: [3][H]
    const float* __restrict__ b1,       // used only when !HASX
    const float* __restrict__ W2, const float* __restrict__ b2,
    float* __restrict__ out) {
  constexpr int HCHUNK = 4096 / C;
  constexpr int CC = C / 64;
  const int i = blockIdx.x, b = blockIdx.y;
  const int tid = threadIdx.x;
  __shared__ float h1s[32 * H];
  __shared__ float sW2[4096];
  __shared__ float rel[32][3];
  __shared__ int snbr[32];
  __shared__ float sRed[4][C];
  const float* __restrict__ pb = pos + (size_t)b * Np * 3;
  if (tid < 32) {
    const int j = nbr[((size_t)b * Np + i) * 32 + tid];
    snbr[tid] = j;
    float rx = 0.f, ry = 0.f, rz = 0.f;
    if (j >= 0) {
      rx = pb[3*j]   - pb[3*i];
      ry = pb[3*j+1] - pb[3*i+1];
      rz = pb[3*j+2] - pb[3*i+2];
    }
    rel[tid][0] = rx; rel[tid][1] = ry; rel[tid][2] = rz;
  }
  __syncthreads();
  // phase B: h1[k][h] = relu(U[j][h] (+b1) + rel . Wrel[:,h]); invalid k -> 0
  for (int idx = tid; idx < 32 * H; idx += 256) {
    const int k = idx / H, h = idx - k * H;
    const int j = snbr[k];
    float v = 0.f;
    if (j >= 0) {
      float a = HASX ? U[((size_t)b * Np + j) * H + h] : b1[h];
      a += rel[k][0] * Wrel[h];
      a += rel[k][1] * Wrel[H + h];
      a += rel[k][2] * Wrel[2 * H + h];
      v = fmaxf(a, 0.f);
    }
    h1s[k * H + h] = v;
  }
  const int cc = tid & 63;
  const int kk = tid >> 6;
  float acc[8][CC];
#pragma unroll
  for (int e = 0; e < 8; e++)
#pragma unroll
    for (int q = 0; q < CC; q++) acc[e][q] = 0.f;
  // phase C: h2 = h1 @ W2, W2 staged in LDS chunks
  for (int hc = 0; hc < H; hc += HCHUNK) {
    __syncthreads();   // also guards phase-B h1s writes on first iteration
    for (int idx = tid; idx < HCHUNK * C; idx += 256) sW2[idx] = W2[(size_t)hc * C + idx];
    __syncthreads();
    for (int hh = 0; hh < HCHUNK; hh++) {
      float wv[CC];
#pragma unroll
      for (int q = 0; q < CC; q++) wv[q] = sW2[hh * C + cc + q * 64];
      const int h = hc + hh;
#pragma unroll
      for (int e = 0; e < 8; e++) {
        const float hv = h1s[(kk + e * 4) * H + h];   // wave-uniform broadcast
#pragma unroll
        for (int q = 0; q < CC; q++) acc[e][q] += hv * wv[q];
      }
    }
  }
  // masked max over k (NEG fill), +b2, relu
  float m[CC];
#pragma unroll
  for (int q = 0; q < CC; q++) m[q] = -1e9f;
#pragma unroll
  for (int e = 0; e < 8; e++) {
    if (snbr[kk + e * 4] >= 0) {
#pragma unroll
      for (int q = 0; q < CC; q++) m[q] = fmaxf(m[q], acc[e][q]);
    }
  }
#pragma unroll
  for (int q = 0; q < CC; q++) sRed[kk][cc + q * 64] = m[q];
  __syncthreads();
  if (kk == 0) {
#pragma unroll
    for (int q = 0; q < CC; q++) {
      const int c = cc + q * 64;
      const float mm = fmaxf(fmaxf(sRed[0][c], sRed[1][c]), fmaxf(sRed[2][c], sRed[3][c]));
      const float o = (mm > -5e8f) ? (mm + b2[c]) : -1e9f;  // no valid nbr -> NEG
      out[((size_t)b * Np + i) * C + c] = fmaxf(o, 0.f);    // fused relu from _forward
    }
  }
}

// ---------------- global max pool + classifier/defense heads ----------------
__global__ __launch_bounds__(256) void head_kernel(
    const float* __restrict__ x3,
    const float* __restrict__ Wc1, const float* __restrict__ bc1,
    const float* __restrict__ Wc2, const float* __restrict__ bc2,
    const float* __restrict__ Wc3, const float* __restrict__ bc3,
    const float* __restrict__ Wd1, const float* __restrict__ bd1,
    const float* __restrict__ Wd2, const float* __restrict__ bd2,
    float* __restrict__ out) {
  const int b = blockIdx.x, tid = threadIdx.x;
  __shared__ float sf[256], sh[256], sh2[256], shd[256], sl[48];
  float mx = -1e9f;
  const float* __restrict__ xb = x3 + (size_t)b * 512 * 256;
  for (int p = 0; p < 512; p++) mx = fmaxf(mx, xb[p * 256 + tid]);
  sf[tid] = mx;
  __syncthreads();
  float a = bc1[tid], ad = bd1[tid];
  for (int f = 0; f < 256; f++) {
    const float fv = sf[f];
    a  = fmaf(fv, Wc1[f * 256 + tid], a);
    ad = fmaf(fv, Wd1[f * 256 + tid], ad);
  }
  sh[tid] = fmaxf(a, 0.f);
  shd[tid] = fmaxf(ad, 0.f);
  __syncthreads();
  float a2 = bc2[tid];
  for (int f = 0; f < 256; f++) a2 = fmaf(sh[f], Wc2[f * 256 + tid], a2);
  sh2[tid] = fmaxf(a2, 0.f);
  __syncthreads();
  if (tid < 40) {
    float l = bc3[tid];
    for (int f = 0; f < 256; f++) l = fmaf(sh2[f], Wc3[f * 40 + tid], l);
    sl[tid] = l;
  }
  if (tid >= 64 && tid < 66) {
    const int q = tid - 64;
    float l = bd2[q];
    for (int f = 0; f < 256; f++) l = fmaf(shd[f], Wd2[f * 2 + q], l);
    sl[40 + q] = l;
  }
  __syncthreads();
  if (tid == 0) {
    float m0 = sl[0];
    for (int q = 1; q < 40; q++) m0 = fmaxf(m0, sl[q]);
    float s = 0.f;
    for (int q = 0; q < 40; q++) s += expf(sl[q] - m0);
    const float ls = logf(s);
    for (int q = 0; q < 40; q++) out[b * 40 + q] = sl[q] - m0 - ls;
    const float m1 = fmaxf(sl[40], sl[41]);
    const float s1 = expf(sl[40] - m1) + expf(sl[41] - m1);
    const float ls1 = logf(s1);
    out[320 + b * 2 + 0] = sl[40] - m1 - ls1;
    out[320 + b * 2 + 1] = sl[41] - m1 - ls1;
  }
}

// ---------------------------------------------------------------------------
extern "C" void kernel_launch(void* const* d_in, const int* in_sizes, int n_in,
                              void* d_out, int out_size, void* d_ws, size_t ws_size,
                              hipStream_t stream) {
  (void)in_sizes; (void)n_in; (void)out_size; (void)ws_size;
  const float* pos = (const float*)d_in[0];
  const float* W1a = (const float*)d_in[1];  const float* b1a = (const float*)d_in[2];
  const float* W1b = (const float*)d_in[3];  const float* b1b = (const float*)d_in[4];
  const float* W2a = (const float*)d_in[5];  const float* b2a = (const float*)d_in[6];
  const float* W2b = (const float*)d_in[7];  const float* b2b = (const float*)d_in[8];
  const float* W3a = (const float*)d_in[9];  const float* b3a = (const float*)d_in[10];
  const float* W3b = (const float*)d_in[11]; const float* b3b = (const float*)d_in[12];
  const float* Wc1 = (const float*)d_in[13]; const float* bc1 = (const float*)d_in[14];
  const float* Wc2 = (const float*)d_in[15]; const float* bc2 = (const float*)d_in[16];
  const float* Wc3 = (const float*)d_in[17]; const float* bc3 = (const float*)d_in[18];
  const float* Wd1 = (const float*)d_in[19]; const float* bd1 = (const float*)d_in[20];
  const float* Wd2 = (const float*)d_in[21]; const float* bd2 = (const float*)d_in[22];
  float* out = (float*)d_out;

  char* w = (char*)d_ws;
  auto alloc = [&](size_t bytes) -> void* {
    void* p = (void*)w;
    w += (bytes + 255) & ~(size_t)255;
    return p;
  };
  int*   nbr1 = (int*)  alloc((size_t)NB*4096*32*4);
  float* x1   = (float*)alloc((size_t)NB*4096*64*4);
  int*   fi1  = (int*)  alloc((size_t)NB*2048*4);
  float* pos2 = (float*)alloc((size_t)NB*2048*3*4);
  float* x1g  = (float*)alloc((size_t)NB*2048*64*4);
  float* U2   = (float*)alloc((size_t)NB*2048*128*4);
  int*   nbr2 = (int*)  alloc((size_t)NB*2048*32*4);
  float* x2   = (float*)alloc((size_t)NB*2048*128*4);
  int*   fi2  = (int*)  alloc((size_t)NB*512*4);
  float* pos3 = (float*)alloc((size_t)NB*512*3*4);
  float* x2g  = (float*)alloc((size_t)NB*512*128*4);
  float* U3   = (float*)alloc((size_t)NB*512*256*4);
  int*   nbr3 = (int*)  alloc((size_t)NB*512*32*4);
  float* x3   = (float*)alloc((size_t)NB*512*256*4);

  // stage 1 (N=4096, r=0.2)
  knn_kernel<4096><<<dim3(4096, NB), 256, 0, stream>>>(pos, 0.2 * 0.2, nbr1);
  conv_kernel<64, 64, false><<<dim3(4096, NB), 256, 0, stream>>>(
      pos, 4096, nbr1, nullptr, W1a, b1a, W1b, b1b, x1);
  fps_kernel<4096, 2048><<<NB, 256, 0, stream>>>(pos, fi1);
  gather_kernel<64><<<NB * 2048, 64, 0, stream>>>(x1, pos, fi1, 4096, 2048, x1g, pos2);

  // stage 2 (N=2048, r=0.4)
  knn_kernel<2048><<<dim3(2048, NB), 256, 0, stream>>>(pos2, 0.4 * 0.4, nbr2);
  preproj_kernel<64, 128><<<NB * 2048, 128, 0, stream>>>(x1g, W2a, b2a, U2);
  conv_kernel<128, 128, true><<<dim3(2048, NB), 256, 0, stream>>>(
      pos2, 2048, nbr2, U2, W2a + (size_t)64 * 128, b2a, W2b, b2b, x2);
  fps_kernel<2048, 512><<<NB, 256, 0, stream>>>(pos2, fi2);
  gather_kernel<128><<<NB * 512, 128, 0, stream>>>(x2, pos2, fi2, 2048, 512, x2g, pos3);

  // stage 3 (N=512, r=1.0)
  knn_kernel<512><<<dim3(512, NB), 256, 0, stream>>>(pos3, 1.0, nbr3);
  preproj_kernel<128, 256><<<NB * 512, 256, 0, stream>>>(x2g, W3a, b3a, U3);
  conv_kernel<256, 256, true><<<dim3(512, NB), 256, 0, stream>>>(
      pos3, 512, nbr3, U3, W3a + (size_t)128 * 256, b3a, W3b, b3b, x3);

  // heads
  head_kernel<<<NB, 256, 0, stream>>>(x3, Wc1, bc1, Wc2, bc2, Wc3, bc3,
                                      Wd1, bd1, Wd2, bd2, out);
}

// Round 7
// 3443.262 us; speedup vs baseline: 1.5093x; 1.0783x over previous
//
#include <hip/hip_runtime.h>

// ---------------------------------------------------------------------------
// PointNet++ (defense variant) forward on MI355X.
// B=8, N=4096 -> 2048 -> 512, K=32 neighbors. Geometry is EXACT: positions are
// multiples of 2^-23, so i32 coords (x*2^23) give d2 = dx^2+dy^2+dz^2 exactly
// in i64 (<2^48) — selection/FPS ranking matches an np-f64 reference exactly.
// R7: conv rewrite — phase B/C fully float4/b128: h1 read as wave-uniform
// b128 broadcast, W2 staged TRANSPOSED+padded (sW2T[c][hh], stride HCHUNK+4)
// so per-lane wv is one b128. Cuts conv LDS issue ~4x (was ~2x over the VALU
// floor per the m134 cycle model; est. ~1.6 ms across the three convs).
// ---------------------------------------------------------------------------

#define NB 8

__device__ __forceinline__ unsigned obits(float f) {
  unsigned u = __float_as_uint(f);
  return (u & 0x80000000u) ? ~u : (u | 0x80000000u);
}

static constexpr int CAND = 1024;

// ---------------- radius-KNN: exact top-32 by (d2, idx) lex order -----------
template<int N>
__global__ __launch_bounds__(256) void knn_kernel(const float* __restrict__ pos,
                                                  double rr, int* __restrict__ nbr) {
  const int i = blockIdx.x, b = blockIdx.y;
  const int tid = threadIdx.x;
  const float* __restrict__ pb = pos + (size_t)b * N * 3;
  __shared__ double d2s[N];
  __shared__ unsigned hist[2048];
  __shared__ unsigned scanBuf[256];
  __shared__ int candIdx[CAND];
  __shared__ int candCnt;
  __shared__ int sBinT;

  const double xi = pb[3*i], yi = pb[3*i+1], zi = pb[3*i+2];
  const double si = (xi*xi + yi*yi) + zi*zi;
  for (int t = tid; t < 2048; t += 256) hist[t] = 0u;
  if (tid == 0) candCnt = 0;
  __syncthreads();
  for (int j = tid; j < N; j += 256) {
    double xj = pb[3*j], yj = pb[3*j+1], zj = pb[3*j+2];
    double sj = (xj*xj + yj*yj) + zj*zj;
    double dt = (xi*xj + yi*yj) + zi*zj;
    double d2 = (si + sj) - 2.0*dt;          // exact in f64 (see header note)
    if (j == i) d2 += 1e9;                   // self-exclusion as in reference
    d2s[j] = d2;
    atomicAdd(&hist[obits((float)d2) >> 21], 1u);
  }
  __syncthreads();
  // find smallest bin T with cumulative count >= 32
  unsigned lsum = 0;
  const int base = tid * 8;
#pragma unroll
  for (int q = 0; q < 8; q++) lsum += hist[base + q];
  scanBuf[tid] = lsum;
  __syncthreads();
  for (int ofs = 1; ofs < 256; ofs <<= 1) {
    unsigned v = scanBuf[tid];
    unsigned addv = (tid >= ofs) ? scanBuf[tid - ofs] : 0u;
    __syncthreads();
    scanBuf[tid] = v + addv;
    __syncthreads();
  }
  const unsigned incl = scanBuf[tid], excl = incl - lsum;
  if (excl < 32u && incl >= 32u) {
    unsigned c = excl;
    for (int q = 0; q < 8; q++) {
      c += hist[base + q];
      if (c >= 32u) { sBinT = base + q; break; }
    }
  }
  __syncthreads();
  const int binT = sBinT;
  for (int j = tid; j < N; j += 256) {
    if ((int)(obits((float)d2s[j]) >> 21) <= binT) {
      int p = atomicAdd(&candCnt, 1);
      if (p < CAND) candIdx[p] = j;
    }
  }
  __syncthreads();
  const int M = min(candCnt, CAND);   // M >= 32 by construction; overflow ~impossible
  int* __restrict__ outp = nbr + ((size_t)b * N + i) * 32;
  for (int c = tid; c < M; c += 256) {
    const int j = candIdx[c];
    const double d = d2s[j];
    int rank = 0;
    for (int e = 0; e < M; e++) {
      const int j2 = candIdx[e];
      const double de = d2s[j2];
      rank += (de < d || (de == d && j2 < j)) ? 1 : 0;
    }
    if (rank < 32) outp[rank] = (d <= rr) ? j : -1;  // fold radius-validity into -1
  }
}

// ---------------- DPP u64-max step (VALU cross-lane, no LDS pipe) -----------
template<int CTRL>
__device__ __forceinline__ unsigned long long dpp_max_step(unsigned long long v) {
  const int lo = (int)(unsigned)(v & 0xffffffffull);
  const int hi = (int)(unsigned)(v >> 32);
  const unsigned nlo = (unsigned)__builtin_amdgcn_update_dpp(lo, lo, CTRL, 0xf, 0xf, false);
  const unsigned nhi = (unsigned)__builtin_amdgcn_update_dpp(hi, hi, CTRL, 0xf, 0xf, false);
  const unsigned long long nv = ((unsigned long long)nhi << 32) | nlo;
  return (nv > v) ? nv : v;
}

// ---------------- farthest point sampling (exact integer, deterministic) ----
// 256 threads (4 waves, 1/SIMD). waves_per_eu(1,1) keeps the ~130-reg point
// state in registers (R5-verified). Coords i32 (x*2^23, exact); mind as
// packed u64 keys: key = (d2 << 12) | (4095 - j) => max key == (max d2, min j).
// Wave reduce: DPP row_shr 1/2/4/8 + row_bcast15/31 -> lane 63 holds wave max.
template<int N, int NOUT>
__global__ __attribute__((amdgpu_waves_per_eu(1, 1)))
__launch_bounds__(256, 1) void fps_kernel(const float* __restrict__ pos,
                                          int* __restrict__ fi) {
  const int b = blockIdx.x;
  const float* __restrict__ pb = pos + (size_t)b * N * 3;
  constexpr int P = N / 256;
  const int tid = threadIdx.x;
  const int wid = tid >> 6, lane = tid & 63;
  int ix[P], iy[P], iz[P];
  unsigned long long mind[P];
  __shared__ int4 sPosI[N];
  __shared__ unsigned long long sKey[2][4];
  __shared__ int sfi[NOUT];
  // stage integer positions into LDS (one-time, read-only afterwards)
  for (int t = tid; t < N; t += 256) {
    sPosI[t] = make_int4((int)(pb[3*t]   * 8388608.f),   // exact: 2^-23 multiples
                         (int)(pb[3*t+1] * 8388608.f),
                         (int)(pb[3*t+2] * 8388608.f), 0);
  }
  __syncthreads();
  const int x0 = sPosI[0].x, y0 = sPosI[0].y, z0 = sPosI[0].z;
  const int invBase = 4095 - tid * P;
  unsigned long long bv;
  {
    unsigned long long tv[P];
#pragma unroll
    for (int e = 0; e < P; e++) {
      const int j = tid * P + e;
      const int4 p4 = sPosI[j];
      ix[e] = p4.x; iy[e] = p4.y; iz[e] = p4.z;
      const long long dx = p4.x - x0, dy = p4.y - y0, dz = p4.z - z0;
      const unsigned long long d2 =
          (unsigned long long)(dx * dx + dy * dy + dz * dz);   // exact, < 2^48
      const unsigned long long k = (d2 << 12) | (unsigned)(invBase - e);
      mind[e] = k; tv[e] = k;
    }
#pragma unroll
    for (int s = 1; s < P; s <<= 1)
#pragma unroll
      for (int e = 0; e + s < P; e += 2 * s)
        if (tv[e + s] > tv[e]) tv[e] = tv[e + s];
    bv = tv[0];
  }
  if (tid == 0) sfi[0] = 0;
  for (int t = 1; t < NOUT; t++) {
    // wave u64-max via DPP (row reduce then cross-row bcasts; result in lane 63)
    unsigned long long v = bv;
    v = dpp_max_step<0x111>(v);   // row_shr:1
    v = dpp_max_step<0x112>(v);   // row_shr:2
    v = dpp_max_step<0x114>(v);   // row_shr:4
    v = dpp_max_step<0x118>(v);   // row_shr:8
    v = dpp_max_step<0x142>(v);   // row_bcast:15
    v = dpp_max_step<0x143>(v);   // row_bcast:31
    const int pp = t & 1;
    if (lane == 63) sKey[pp][wid] = v;
    __syncthreads();   // the only barrier per iteration; drains LDS only (no
                       // global stores in the loop -> no vmcnt(0) stall)
    // all threads redundantly reduce the 4 wave partials (2-level tree)
    unsigned long long k0 = sKey[pp][0], k1 = sKey[pp][1],
                       k2 = sKey[pp][2], k3 = sKey[pp][3];
    k0 = (k1 > k0) ? k1 : k0;
    k2 = (k3 > k2) ? k3 : k2;
    k0 = (k2 > k0) ? k2 : k0;
    const int ii = 4095 - (int)(k0 & 0xFFFull);   // global winner index
    if (tid == 0) sfi[t] = ii;
    // winner coords: single ds_read_b128, conflict-free same-address broadcast
    const int4 wc = sPosI[ii];
    // fused update + pairwise-tree rescan (keys only; identity rides low bits)
    unsigned long long tv[P];
#pragma unroll
    for (int e = 0; e < P; e++) {
      const long long dx = ix[e] - wc.x, dy = iy[e] - wc.y, dz = iz[e] - wc.z;
      const unsigned long long nd =
          (unsigned long long)(dx * dx + dy * dy + dz * dz);
      const unsigned long long nk = (nd << 12) | (unsigned)(invBase - e);
      unsigned long long mk = mind[e];
      mk = (nk < mk) ? nk : mk;
      mind[e] = mk;
      tv[e] = mk;
    }
#pragma unroll
    for (int s = 1; s < P; s <<= 1)
#pragma unroll
      for (int e = 0; e + s < P; e += 2 * s)
        if (tv[e + s] > tv[e]) tv[e] = tv[e + s];
    bv = tv[0];
  }
  // flush the index buffer to global (coalesced, once)
  __syncthreads();
  for (int t = tid; t < NOUT; t += 256) fi[(size_t)b * NOUT + t] = sfi[t];
}

// ---------------- gather rows by fps indices --------------------------------
template<int CIN>
__global__ void gather_kernel(const float* __restrict__ X, const float* __restrict__ pos,
                              const int* __restrict__ fi, int N, int M,
                              float* __restrict__ Xg, float* __restrict__ posg) {
  const int row = blockIdx.x;
  const int b = row / M;
  const int tid = threadIdx.x;
  const int j = fi[row];
  if (tid < CIN) Xg[(size_t)row * CIN + tid] = X[((size_t)b * N + j) * CIN + tid];
  if (tid < 3) posg[(size_t)row * 3 + tid] = pos[((size_t)b * N + j) * 3 + tid];
}

// ---------------- per-source-point projection U = x*W1[:CIN] + b1 -----------
template<int CIN, int H>
__global__ void preproj_kernel(const float* __restrict__ X, const float* __restrict__ W,
                               const float* __restrict__ bias, float* __restrict__ U) {
  const int row = blockIdx.x;
  const int tid = threadIdx.x;
  __shared__ float sx[CIN];
  if (tid < CIN) sx[tid] = X[(size_t)row * CIN + tid];
  __syncthreads();
  float a = bias[tid];
  for (int f = 0; f < CIN; f++) a = fmaf(sx[f], W[f * H + tid], a);
  U[(size_t)row * H + tid] = a;
}

// ---------------- fused PointConv (edge MLP + masked max + relu) ------------
// 256 threads = 4 k-groups (kk) x 64 c-lanes (cc); each thread: 8 k's x CC c's.
// Phase C: W2 chunk staged TRANSPOSED (sW2T[c][hh], stride HCHUNK+4 -> 16B
// aligned, bank-uniform); per 4 hh's: one b128 per wv + one wave-uniform b128
// broadcast per h1 row. VALU-bound by the fma count.
template<int H, int C, bool HASX>
__global__ __launch_bounds__(256) void conv_kernel(
    const float* __restrict__ pos, int Np,
    const int* __restrict__ nbr,
    const float* __restrict__ U,        // [B*Np, H] (x*W1x + b1) or nullptr
    const float* __restrict__ Wrel,     // rel rows of W1: [3][H]
    const float* __restrict__ b1,       // used only when !HASX
    const float* __restrict__ W2, const float* __restrict__ b2,
    float* __restrict__ out) {
  constexpr int HCHUNK = (C == 64) ? 64 : (C == 128 ? 32 : 16);
  constexpr int STR = HCHUNK + 4;     // padded row stride (multiple of 4: b128 ok)
  constexpr int CC = C / 64;
  constexpr int QPK = H / 4;          // float4 quads per k-row
  const int i = blockIdx.x, b = blockIdx.y;
  const int tid = threadIdx.x;
  __shared__ __align__(16) float h1s[32 * H];
  __shared__ __align__(16) float sW2T[C * STR];
  __shared__ float rel[32][3];
  __shared__ int snbr[32];
  __shared__ float sRed[4][C];
  const float* __restrict__ pb = pos + (size_t)b * Np * 3;
  if (tid < 32) {
    const int j = nbr[((size_t)b * Np + i) * 32 + tid];
    snbr[tid] = j;
    float rx = 0.f, ry = 0.f, rz = 0.f;
    if (j >= 0) {
      rx = pb[3*j]   - pb[3*i];
      ry = pb[3*j+1] - pb[3*i+1];
      rz = pb[3*j+2] - pb[3*i+2];
    }
    rel[tid][0] = rx; rel[tid][1] = ry; rel[tid][2] = rz;
  }
  __syncthreads();
  // phase B (vectorized): h1[k][h0..h0+3] = relu(U[j] (+b1) + rel . Wrel)
  for (int qi = tid; qi < 32 * QPK; qi += 256) {
    const int k = qi / QPK, hq = qi - k * QPK, h0 = hq * 4;
    const int j = snbr[k];
    float4 v = make_float4(0.f, 0.f, 0.f, 0.f);
    if (j >= 0) {
      float4 a = HASX ? *(const float4*)&U[((size_t)b * Np + j) * H + h0]
                      : *(const float4*)&b1[h0];
      const float rx = rel[k][0], ry = rel[k][1], rz = rel[k][2];
      const float4 w0 = *(const float4*)&Wrel[h0];
      const float4 w1 = *(const float4*)&Wrel[H + h0];
      const float4 w2 = *(const float4*)&Wrel[2 * H + h0];
      a.x += rx * w0.x + ry * w1.x + rz * w2.x;
      a.y += rx * w0.y + ry * w1.y + rz * w2.y;
      a.z += rx * w0.z + ry * w1.z + rz * w2.z;
      a.w += rx * w0.w + ry * w1.w + rz * w2.w;
      v = make_float4(fmaxf(a.x, 0.f), fmaxf(a.y, 0.f),
                      fmaxf(a.z, 0.f), fmaxf(a.w, 0.f));
    }
    *(float4*)&h1s[k * H + h0] = v;
  }
  const int cc = tid & 63;
  const int kk = tid >> 6;
  float acc[8][CC];
#pragma unroll
  for (int e = 0; e < 8; e++)
#pragma unroll
    for (int q = 0; q < CC; q++) acc[e][q] = 0.f;
  // phase C: h2 = h1 @ W2; chunk staged transposed into sW2T
  for (int hc = 0; hc < H; hc += HCHUNK) {
    __syncthreads();   // also guards phase-B h1s writes on first iteration
    for (int idx = tid; idx < HCHUNK * C; idx += 256) {
      const int hh = idx / C, c = idx - hh * C;
      sW2T[c * STR + hh] = W2[(size_t)(hc + hh) * C + c];
    }
    __syncthreads();
    for (int hh0 = 0; hh0 < HCHUNK; hh0 += 4) {
      float4 wv[CC];
#pragma unroll
      for (int q = 0; q < CC; q++)
        wv[q] = *(const float4*)&sW2T[(cc + q * 64) * STR + hh0];
#pragma unroll
      for (int e = 0; e < 8; e++) {
        const float4 hv = *(const float4*)&h1s[(kk + e * 4) * H + hc + hh0];
#pragma unroll
        for (int q = 0; q < CC; q++) {
          acc[e][q] += hv.x * wv[q].x;
          acc[e][q] += hv.y * wv[q].y;
          acc[e][q] += hv.z * wv[q].z;
          acc[e][q] += hv.w * wv[q].w;
        }
      }
    }
  }
  // masked max over k (NEG fill), +b2, relu
  float m[CC];
#pragma unroll
  for (int q = 0; q < CC; q++) m[q] = -1e9f;
#pragma unroll
  for (int e = 0; e < 8; e++) {
    if (snbr[kk + e * 4] >= 0) {
#pragma unroll
      for (int q = 0; q < CC; q++) m[q] = fmaxf(m[q], acc[e][q]);
    }
  }
#pragma unroll
  for (int q = 0; q < CC; q++) sRed[kk][cc + q * 64] = m[q];
  __syncthreads();
  if (kk == 0) {
#pragma unroll
    for (int q = 0; q < CC; q++) {
      const int c = cc + q * 64;
      const float mm = fmaxf(fmaxf(sRed[0][c], sRed[1][c]), fmaxf(sRed[2][c], sRed[3][c]));
      const float o = (mm > -5e8f) ? (mm + b2[c]) : -1e9f;  // no valid nbr -> NEG
      out[((size_t)b * Np + i) * C + c] = fmaxf(o, 0.f);    // fused relu from _forward
    }
  }
}

// ---------------- global max pool + classifier/defense heads ----------------
__global__ __launch_bounds__(256) void head_kernel(
    const float* __restrict__ x3,
    const float* __restrict__ Wc1, const float* __restrict__ bc1,
    const float* __restrict__ Wc2, const float* __restrict__ bc2,
    const float* __restrict__ Wc3, const float* __restrict__ bc3,
    const float* __restrict__ Wd1, const float* __restrict__ bd1,
    const float* __restrict__ Wd2, const float* __restrict__ bd2,
    float* __restrict__ out) {
  const int b = blockIdx.x, tid = threadIdx.x;
  __shared__ float sf[256], sh[256], sh2[256], shd[256], sl[48];
  float mx = -1e9f;
  const float* __restrict__ xb = x3 + (size_t)b * 512 * 256;
  for (int p = 0; p < 512; p++) mx = fmaxf(mx, xb[p * 256 + tid]);
  sf[tid] = mx;
  __syncthreads();
  float a = bc1[tid], ad = bd1[tid];
  for (int f = 0; f < 256; f++) {
    const float fv = sf[f];
    a  = fmaf(fv, Wc1[f * 256 + tid], a);
    ad = fmaf(fv, Wd1[f * 256 + tid], ad);
  }
  sh[tid] = fmaxf(a, 0.f);
  shd[tid] = fmaxf(ad, 0.f);
  __syncthreads();
  float a2 = bc2[tid];
  for (int f = 0; f < 256; f++) a2 = fmaf(sh[f], Wc2[f * 256 + tid], a2);
  sh2[tid] = fmaxf(a2, 0.f);
  __syncthreads();
  if (tid < 40) {
    float l = bc3[tid];
    for (int f = 0; f < 256; f++) l = fmaf(sh2[f], Wc3[f * 40 + tid], l);
    sl[tid] = l;
  }
  if (tid >= 64 && tid < 66) {
    const int q = tid - 64;
    float l = bd2[q];
    for (int f = 0; f < 256; f++) l = fmaf(shd[f], Wd2[f * 2 + q], l);
    sl[40 + q] = l;
  }
  __syncthreads();
  if (tid == 0) {
    float m0 = sl[0];
    for (int q = 1; q < 40; q++) m0 = fmaxf(m0, sl[q]);
    float s = 0.f;
    for (int q = 0; q < 40; q++) s += expf(sl[q] - m0);
    const float ls = logf(s);
    for (int q = 0; q < 40; q++) out[b * 40 + q] = sl[q] - m0 - ls;
    const float m1 = fmaxf(sl[40], sl[41]);
    const float s1 = expf(sl[40] - m1) + expf(sl[41] - m1);
    const float ls1 = logf(s1);
    out[320 + b * 2 + 0] = sl[40] - m1 - ls1;
    out[320 + b * 2 + 1] = sl[41] - m1 - ls1;
  }
}

// ---------------------------------------------------------------------------
extern "C" void kernel_launch(void* const* d_in, const int* in_sizes, int n_in,
                              void* d_out, int out_size, void* d_ws, size_t ws_size,
                              hipStream_t stream) {
  (void)in_sizes; (void)n_in; (void)out_size; (void)ws_size;
  const float* pos = (const float*)d_in[0];
  const float* W1a = (const float*)d_in[1];  const float* b1a = (const float*)d_in[2];
  const float* W1b = (const float*)d_in[3];  const float* b1b = (const float*)d_in[4];
  const float* W2a = (const float*)d_in[5];  const float* b2a = (const float*)d_in[6];
  const float* W2b = (const float*)d_in[7];  const float* b2b = (const float*)d_in[8];
  const float* W3a = (const float*)d_in[9];  const float* b3a = (const float*)d_in[10];
  const float* W3b = (const float*)d_in[11]; const float* b3b = (const float*)d_in[12];
  const float* Wc1 = (const float*)d_in[13]; const float* bc1 = (const float*)d_in[14];
  const float* Wc2 = (const float*)d_in[15]; const float* bc2 = (const float*)d_in[16];
  const float* Wc3 = (const float*)d_in[17]; const float* bc3 = (const float*)d_in[18];
  const float* Wd1 = (const float*)d_in[19]; const float* bd1 = (const float*)d_in[20];
  const float* Wd2 = (const float*)d_in[21]; const float* bd2 = (const float*)d_in[22];
  float* out = (float*)d_out;

  char* w = (char*)d_ws;
  auto alloc = [&](size_t bytes) -> void* {
    void* p = (void*)w;
    w += (bytes + 255) & ~(size_t)255;
    return p;
  };
  int*   nbr1 = (int*)  alloc((size_t)NB*4096*32*4);
  float* x1   = (float*)alloc((size_t)NB*4096*64*4);
  int*   fi1  = (int*)  alloc((size_t)NB*2048*4);
  float* pos2 = (float*)alloc((size_t)NB*2048*3*4);
  float* x1g  = (float*)alloc((size_t)NB*2048*64*4);
  float* U2   = (float*)alloc((size_t)NB*2048*128*4);
  int*   nbr2 = (int*)  alloc((size_t)NB*2048*32*4);
  float* x2   = (float*)alloc((size_t)NB*2048*128*4);
  int*   fi2  = (int*)  alloc((size_t)NB*512*4);
  float* pos3 = (float*)alloc((size_t)NB*512*3*4);
  float* x2g  = (float*)alloc((size_t)NB*512*128*4);
  float* U3   = (float*)alloc((size_t)NB*512*256*4);
  int*   nbr3 = (int*)  alloc((size_t)NB*512*32*4);
  float* x3   = (float*)alloc((size_t)NB*512*256*4);

  // stage 1 (N=4096, r=0.2)
  knn_kernel<4096><<<dim3(4096, NB), 256, 0, stream>>>(pos, 0.2 * 0.2, nbr1);
  conv_kernel<64, 64, false><<<dim3(4096, NB), 256, 0, stream>>>(
      pos, 4096, nbr1, nullptr, W1a, b1a, W1b, b1b, x1);
  fps_kernel<4096, 2048><<<NB, 256, 0, stream>>>(pos, fi1);
  gather_kernel<64><<<NB * 2048, 64, 0, stream>>>(x1, pos, fi1, 4096, 2048, x1g, pos2);

  // stage 2 (N=2048, r=0.4)
  knn_kernel<2048><<<dim3(2048, NB), 256, 0, stream>>>(pos2, 0.4 * 0.4, nbr2);
  preproj_kernel<64, 128><<<NB * 2048, 128, 0, stream>>>(x1g, W2a, b2a, U2);
  conv_kernel<128, 128, true><<<dim3(2048, NB), 256, 0, stream>>>(
      pos2, 2048, nbr2, U2, W2a + (size_t)64 * 128, b2a, W2b, b2b, x2);
  fps_kernel<2048, 512><<<NB, 256, 0, stream>>>(pos2, fi2);
  gather_kernel<128><<<NB * 512, 128, 0, stream>>>(x2, pos2, fi2, 2048, 512, x2g, pos3);

  // stage 3 (N=512, r=1.0)
  knn_kernel<512><<<dim3(512, NB), 256, 0, stream>>>(pos3, 1.0, nbr3);
  preproj_kernel<128, 256><<<NB * 512, 256, 0, stream>>>(x2g, W3a, b3a, U3);
  conv_kernel<256, 256, true><<<dim3(512, NB), 256, 0, stream>>>(
      pos3, 512, nbr3, U3, W3a + (size_t)128 * 256, b3a, W3b, b3b, x3);

  // heads
  head_kernel<<<NB, 256, 0, stream>>>(x3, Wc1, bc1, Wc2, bc2, Wc3, bc3,
                                      Wd1, bd1, Wd2, bd2, out);
}